// Round 1
// baseline (742.173 us; speedup 1.0000x reference)
//
#include <hip/hip_runtime.h>

typedef unsigned int u32;
typedef unsigned short u16;
typedef __attribute__((ext_vector_type(8))) short bf16x8;   // 8 bf16 in 4 VGPRs
typedef __attribute__((ext_vector_type(4))) float f32x4;

#define DF 128

__device__ __forceinline__ float bf2f(u32 h) { return __uint_as_float(h << 16); }
__device__ __forceinline__ u16 f2bf(float f) {
  u32 u = __float_as_uint(f);
  u32 r = (u + 0x7fffu + ((u >> 16) & 1u)) >> 16;   // RNE
  return (u16)r;
}
__device__ __forceinline__ u32 pack2(float a, float b) {
  return (u32)f2bf(a) | ((u32)f2bf(b) << 16);
}

// ---------- generic f32 -> bf16 conversion (x, W1, W2) ----------
__global__ void k_cvt_f32_bf16(const float* __restrict__ in, u16* __restrict__ out, int n4) {
  int i = blockIdx.x * blockDim.x + threadIdx.x;
  if (i >= n4) return;
  float4 v = ((const float4*)in)[i];
  ((uint2*)out)[i] = make_uint2(pack2(v.x, v.y), pack2(v.z, v.w));
}

// ---------- CSR build ----------
__global__ void k_hist(const int* __restrict__ dst, int* __restrict__ deg, int E, int N) {
  int e = blockIdx.x * blockDim.x + threadIdx.x;
  if (e < E) { u32 d = (u32)dst[e]; if (d < (u32)N) atomicAdd(&deg[d], 1); }
}

__global__ void k_scan1(const int* __restrict__ deg, int* __restrict__ part,
                        int* __restrict__ bsum, int N) {
  __shared__ int sh[256];
  int t = threadIdx.x, i = blockIdx.x * 256 + t;
  int v = (i < N) ? deg[i] : 0;
  sh[t] = v; __syncthreads();
  for (int o = 1; o < 256; o <<= 1) {
    int tv = (t >= o) ? sh[t - o] : 0;
    __syncthreads();
    sh[t] += tv;
    __syncthreads();
  }
  if (i < N) part[i] = sh[t] - v;            // exclusive
  if (t == 255) bsum[blockIdx.x] = sh[255];  // block total
}

__global__ void k_scan2(int* bsum, int nb) {
  if (blockIdx.x == 0 && threadIdx.x == 0) {
    int run = 0;
    for (int b = 0; b < nb; b++) { int t = bsum[b]; bsum[b] = run; run += t; }
  }
}

__global__ void k_scan3(int* __restrict__ rowptr, const int* __restrict__ bsum,
                        int* __restrict__ cursor, int N, int E) {
  int i = blockIdx.x * blockDim.x + threadIdx.x;
  if (i < N) {
    int v = rowptr[i] + bsum[i >> 8];
    rowptr[i] = v; cursor[i] = v;
  }
  if (i == N) rowptr[N] = E;
}

__global__ void k_scatter(const int* __restrict__ src, const int* __restrict__ dstv,
                          int* __restrict__ cursor, int* __restrict__ adj, int E, int N) {
  int e = blockIdx.x * blockDim.x + threadIdx.x;
  if (e < E) {
    u32 d = (u32)dstv[e];
    if (d < (u32)N) {
      int p = atomicAdd(&cursor[d], 1);
      adj[p] = src[e];
    }
  }
}

// ---------- aggregation: z = (1+eps)*h + sum_{e:dst==n} relu(h[src]) ----------
// one wave per node; lane holds 2 features (uint = 2 bf16)
__global__ void k_aggr(const u16* __restrict__ h, const int* __restrict__ rowptr,
                       const int* __restrict__ adj, const float* __restrict__ epsArr,
                       int layer, u16* __restrict__ z, int N) {
  int wid = (blockIdx.x * blockDim.x + threadIdx.x) >> 6;
  int lane = threadIdx.x & 63;
  if (wid >= N) return;
  const u32* h32 = (const u32*)h;
  float e1 = 1.0f + epsArr[layer];
  u32 pv = h32[wid * 64 + lane];
  float a0 = e1 * bf2f(pv & 0xffffu);
  float a1 = e1 * bf2f(pv >> 16);
  int b = rowptr[wid], e = rowptr[wid + 1];
  for (; b < e; b++) {
    int s = adj[b];
    u32 v = h32[(u32)s * 64 + lane];
    a0 += fmaxf(bf2f(v & 0xffffu), 0.0f);
    a1 += fmaxf(bf2f(v >> 16), 0.0f);
  }
  ((u32*)z)[wid * 64 + lane] = pack2(a0, a1);
}

// ---------- GEMM: out[r][c] = sum_k in[r][k] * W[c][k] + bias[c]  (bf16 MFMA) ----------
// optional input transform: in' = relu(a[k]*in + c[k])  (fused BN+ReLU of previous stage)
// accumulates column sum / sumsq of f32 outputs into statS/statQ (valid rows only)
// LDS tiles stored in MFMA fragment order: slot = ((kt*8 + tile)*64 + lane), 16B/lane
__global__ __launch_bounds__(256, 2) void k_gemm(
    const u16* __restrict__ A, const u16* __restrict__ W, const float* __restrict__ bias,
    const float* __restrict__ ain, const float* __restrict__ cin, int trans,
    float* __restrict__ statS, float* __restrict__ statQ,
    u16* __restrict__ out, int Nrows) {
  __shared__ u16 lA[4 * 8 * 64 * 8];  // 32 KB
  __shared__ u16 lB[4 * 8 * 64 * 8];  // 32 KB
  int tid = threadIdx.x;
  int rowBase = blockIdx.x * 128;

  // stage A (z rows) in fragment order
  #pragma unroll
  for (int cc = 0; cc < 8; cc++) {
    int c = tid + cc * 256;
    int lane = c & 63, rt = (c >> 6) & 7, kt = c >> 9;
    int m = lane & 15, quad = lane >> 4;
    int grow = rowBase + rt * 16 + m;
    int gk = kt * 32 + quad * 8;
    uint4 val = make_uint4(0, 0, 0, 0);
    if (grow < Nrows) val = *(const uint4*)(A + (size_t)grow * DF + gk);
    if (trans) {
      float4 av0 = *(const float4*)(ain + gk);
      float4 av1 = *(const float4*)(ain + gk + 4);
      float4 cv0 = *(const float4*)(cin + gk);
      float4 cv1 = *(const float4*)(cin + gk + 4);
      float f0 = fmaxf(fmaf(av0.x, bf2f(val.x & 0xffffu), cv0.x), 0.0f);
      float f1 = fmaxf(fmaf(av0.y, bf2f(val.x >> 16),     cv0.y), 0.0f);
      float f2 = fmaxf(fmaf(av0.z, bf2f(val.y & 0xffffu), cv0.z), 0.0f);
      float f3 = fmaxf(fmaf(av0.w, bf2f(val.y >> 16),     cv0.w), 0.0f);
      float f4 = fmaxf(fmaf(av1.x, bf2f(val.z & 0xffffu), cv1.x), 0.0f);
      float f5 = fmaxf(fmaf(av1.y, bf2f(val.z >> 16),     cv1.y), 0.0f);
      float f6 = fmaxf(fmaf(av1.z, bf2f(val.w & 0xffffu), cv1.z), 0.0f);
      float f7 = fmaxf(fmaf(av1.w, bf2f(val.w >> 16),     cv1.w), 0.0f);
      val = make_uint4(pack2(f0, f1), pack2(f2, f3), pack2(f4, f5), pack2(f6, f7));
    }
    ((uint4*)lA)[c] = val;
  }
  // stage B (W rows, [c][k]) in fragment order
  #pragma unroll
  for (int cc = 0; cc < 8; cc++) {
    int c = tid + cc * 256;
    int lane = c & 63, ct = (c >> 6) & 7, kt = c >> 9;
    int n = lane & 15, quad = lane >> 4;
    ((uint4*)lB)[c] = *(const uint4*)(W + (ct * 16 + n) * DF + kt * 32 + quad * 8);
  }
  __syncthreads();

  int lane = tid & 63, w = tid >> 6;
  int rq = w >> 1, cq = w & 1;  // wave -> 64x64 quadrant
  f32x4 acc[4][4];
  #pragma unroll
  for (int i = 0; i < 4; i++)
    #pragma unroll
    for (int j = 0; j < 4; j++) acc[i][j] = (f32x4){0.f, 0.f, 0.f, 0.f};

  const bf16x8* pA = (const bf16x8*)lA;
  const bf16x8* pB = (const bf16x8*)lB;
  #pragma unroll
  for (int kt = 0; kt < 4; kt++) {
    bf16x8 af[4], bfr[4];
    #pragma unroll
    for (int i = 0; i < 4; i++) af[i] = pA[(kt * 8 + rq * 4 + i) * 64 + lane];
    #pragma unroll
    for (int j = 0; j < 4; j++) bfr[j] = pB[(kt * 8 + cq * 4 + j) * 64 + lane];
    #pragma unroll
    for (int i = 0; i < 4; i++)
      #pragma unroll
      for (int j = 0; j < 4; j++)
        acc[i][j] = __builtin_amdgcn_mfma_f32_16x16x32_bf16(af[i], bfr[j], acc[i][j], 0, 0, 0);
  }

  // epilogue: bias, store bf16, per-column stats
  int mcol = lane & 15, quad = lane >> 4;
  float colS[4] = {0, 0, 0, 0}, colQ[4] = {0, 0, 0, 0};
  #pragma unroll
  for (int j = 0; j < 4; j++) {
    int col = (cq * 4 + j) * 16 + mcol;
    float bv = bias[col];
    #pragma unroll
    for (int i = 0; i < 4; i++) {
      int row0 = rowBase + (rq * 4 + i) * 16 + quad * 4;
      #pragma unroll
      for (int r = 0; r < 4; r++) {
        int row = row0 + r;
        if (row < Nrows) {
          float v = acc[i][j][r] + bv;
          out[(size_t)row * DF + col] = f2bf(v);
          colS[j] += v;
          colQ[j] += v * v;
        }
      }
    }
  }
  #pragma unroll
  for (int j = 0; j < 4; j++) {
    float s = colS[j], q = colQ[j];
    s += __shfl_xor(s, 16); q += __shfl_xor(q, 16);
    s += __shfl_xor(s, 32); q += __shfl_xor(q, 32);
    if (quad == 0) {
      int col = (cq * 4 + j) * 16 + mcol;
      atomicAdd(&statS[col], s);
      atomicAdd(&statQ[col], q);
    }
  }
}

// ---------- finalize BN stats into affine a,c ----------
__global__ void k_finalize(const float* __restrict__ s, const float* __restrict__ q,
                           const float* __restrict__ gamma, const float* __restrict__ beta,
                           float* __restrict__ a, float* __restrict__ c, int Nrows) {
  int t = threadIdx.x;
  if (t < DF) {
    float inv_n = 1.0f / (float)Nrows;
    float mean = s[t] * inv_n;
    float var = fmaxf(q[t] * inv_n - mean * mean, 0.0f);
    float iv = rsqrtf(var + 1e-5f);
    float av = gamma[t] * iv;
    a[t] = av;
    c[t] = beta[t] - mean * av;
  }
}

// ---------- BN apply (bf16 out, optional relu) ----------
__global__ void k_bnapply_bf16(const u16* __restrict__ u, const float* __restrict__ a,
                               const float* __restrict__ c, u16* __restrict__ h, int n8, int relu) {
  int i = blockIdx.x * blockDim.x + threadIdx.x;
  if (i >= n8) return;
  int col = (i * 8) & 127;
  float4 a0 = *(const float4*)(a + col), a1v = *(const float4*)(a + col + 4);
  float4 c0 = *(const float4*)(c + col), c1v = *(const float4*)(c + col + 4);
  uint4 v = ((const uint4*)u)[i];
  float f0 = fmaf(a0.x, bf2f(v.x & 0xffffu), c0.x);
  float f1 = fmaf(a0.y, bf2f(v.x >> 16),     c0.y);
  float f2 = fmaf(a0.z, bf2f(v.y & 0xffffu), c0.z);
  float f3 = fmaf(a0.w, bf2f(v.y >> 16),     c0.w);
  float f4 = fmaf(a1v.x, bf2f(v.z & 0xffffu), c1v.x);
  float f5 = fmaf(a1v.y, bf2f(v.z >> 16),     c1v.y);
  float f6 = fmaf(a1v.z, bf2f(v.w & 0xffffu), c1v.z);
  float f7 = fmaf(a1v.w, bf2f(v.w >> 16),     c1v.w);
  if (relu) {
    f0 = fmaxf(f0, 0.f); f1 = fmaxf(f1, 0.f); f2 = fmaxf(f2, 0.f); f3 = fmaxf(f3, 0.f);
    f4 = fmaxf(f4, 0.f); f5 = fmaxf(f5, 0.f); f6 = fmaxf(f6, 0.f); f7 = fmaxf(f7, 0.f);
  }
  ((uint4*)h)[i] = make_uint4(pack2(f0, f1), pack2(f2, f3), pack2(f4, f5), pack2(f6, f7));
}

// ---------- BN apply, f32 out (final layer, no relu) ----------
__global__ void k_bnapply_f32(const u16* __restrict__ u, const float* __restrict__ a,
                              const float* __restrict__ c, float* __restrict__ out, int n8) {
  int i = blockIdx.x * blockDim.x + threadIdx.x;
  if (i >= n8) return;
  int col = (i * 8) & 127;
  float4 a0 = *(const float4*)(a + col), a1v = *(const float4*)(a + col + 4);
  float4 c0 = *(const float4*)(c + col), c1v = *(const float4*)(c + col + 4);
  uint4 v = ((const uint4*)u)[i];
  float4 o0, o1;
  o0.x = fmaf(a0.x, bf2f(v.x & 0xffffu), c0.x);
  o0.y = fmaf(a0.y, bf2f(v.x >> 16),     c0.y);
  o0.z = fmaf(a0.z, bf2f(v.y & 0xffffu), c0.z);
  o0.w = fmaf(a0.w, bf2f(v.y >> 16),     c0.w);
  o1.x = fmaf(a1v.x, bf2f(v.z & 0xffffu), c1v.x);
  o1.y = fmaf(a1v.y, bf2f(v.z >> 16),     c1v.y);
  o1.z = fmaf(a1v.z, bf2f(v.w & 0xffffu), c1v.z);
  o1.w = fmaf(a1v.w, bf2f(v.w >> 16),     c1v.w);
  ((float4*)out)[i * 2] = o0;
  ((float4*)out)[i * 2 + 1] = o1;
}

extern "C" void kernel_launch(void* const* d_in, const int* in_sizes, int n_in,
                              void* d_out, int out_size, void* d_ws, size_t ws_size,
                              hipStream_t stream) {
  const float* x    = (const float*)d_in[0];
  const int*   ei   = (const int*)d_in[1];
  const float* W1   = (const float*)d_in[2];
  const float* b1   = (const float*)d_in[3];
  const float* g1   = (const float*)d_in[4];
  const float* bt1  = (const float*)d_in[5];
  const float* W2   = (const float*)d_in[6];
  const float* b2   = (const float*)d_in[7];
  const float* eps  = (const float*)d_in[8];
  const float* gout = (const float*)d_in[9];
  const float* btout= (const float*)d_in[10];

  int N = in_sizes[0] / DF;
  int E = in_sizes[1] / 2;
  int L = in_sizes[8];

  char* ws = (char*)d_ws;
  size_t off = 0;
  auto alloc = [&](size_t bytes) -> void* {
    void* p = ws + off;
    off += (bytes + 255) & ~(size_t)255;
    return p;
  };
  u16* bufA   = (u16*)alloc((size_t)N * DF * 2);
  u16* bufB   = (u16*)alloc((size_t)N * DF * 2);
  int* degcur = (int*)alloc((size_t)N * 4);
  int* rowptr = (int*)alloc((size_t)(N + 1) * 4);
  int* adj    = (int*)alloc((size_t)E * 4);
  int* bsum   = (int*)alloc(4096);
  u16* W1b    = (u16*)alloc((size_t)L * DF * DF * 2);
  u16* W2b    = (u16*)alloc((size_t)L * DF * DF * 2);
  float* stats= (float*)alloc((size_t)L * 4 * DF * 4);
  float* coefs= (float*)alloc((size_t)L * 4 * DF * 4);

  hipMemsetAsync(degcur, 0, (size_t)N * 4, stream);
  hipMemsetAsync(stats, 0, (size_t)L * 4 * DF * 4, stream);

  int n4x = N * DF / 4;
  k_cvt_f32_bf16<<<(n4x + 255) / 256, 256, 0, stream>>>(x, bufA, n4x);
  int n4w = L * DF * DF / 4;
  k_cvt_f32_bf16<<<(n4w + 255) / 256, 256, 0, stream>>>(W1, W1b, n4w);
  k_cvt_f32_bf16<<<(n4w + 255) / 256, 256, 0, stream>>>(W2, W2b, n4w);

  const int* srcI = ei;
  const int* dstI = ei + E;
  int nb = (N + 255) / 256;
  k_hist<<<(E + 255) / 256, 256, 0, stream>>>(dstI, degcur, E, N);
  k_scan1<<<nb, 256, 0, stream>>>(degcur, rowptr, bsum, N);
  k_scan2<<<1, 64, 0, stream>>>(bsum, nb);
  k_scan3<<<(N + 256) / 256, 256, 0, stream>>>(rowptr, bsum, degcur, N, E);
  k_scatter<<<(E + 255) / 256, 256, 0, stream>>>(srcI, dstI, degcur, adj, E, N);

  u16* H = bufA;   // holds h (bf16)
  u16* Z = bufB;   // scratch
  int gblocks = (N + 127) / 128;
  int n8 = N * DF / 8;
  for (int l = 0; l < L; l++) {
    float* S1 = stats + l * 4 * DF; float* Q1 = S1 + DF; float* S2 = Q1 + DF; float* Q2 = S2 + DF;
    float* a1 = coefs + l * 4 * DF; float* c1 = a1 + DF; float* a2 = c1 + DF; float* c2 = a2 + DF;
    // z0 = (1+eps)h + aggr(relu(h))           H -> Z
    k_aggr<<<(N + 3) / 4, 256, 0, stream>>>(H, rowptr, adj, eps, l, Z, N);
    // t = z0 @ W1^T + b1, stats              Z -> H
    k_gemm<<<gblocks, 256, 0, stream>>>(Z, W1b + l * DF * DF, b1 + l * DF,
                                        nullptr, nullptr, 0, S1, Q1, H, N);
    k_finalize<<<1, 128, 0, stream>>>(S1, Q1, g1 + l * DF, bt1 + l * DF, a1, c1, N);
    // u = relu(BN1(t)) @ W2^T + b2, stats    H -> Z
    k_gemm<<<gblocks, 256, 0, stream>>>(H, W2b + l * DF * DF, b2 + l * DF,
                                        a1, c1, 1, S2, Q2, Z, N);
    k_finalize<<<1, 128, 0, stream>>>(S2, Q2, gout + l * DF, btout + l * DF, a2, c2, N);
    // h' = act(BN2(u))                       Z -> H (or d_out, f32, final)
    if (l < L - 1) {
      k_bnapply_bf16<<<(n8 + 255) / 256, 256, 0, stream>>>(Z, a2, c2, H, n8, 1);
    } else {
      k_bnapply_f32<<<(n8 + 255) / 256, 256, 0, stream>>>(Z, a2, c2, (float*)d_out, n8);
    }
  }
}

// Round 2
// 657.858 us; speedup vs baseline: 1.1282x; 1.1282x over previous
//
#include <hip/hip_runtime.h>

typedef unsigned int u32;
typedef unsigned short u16;
typedef __attribute__((ext_vector_type(8))) short bf16x8;   // 8 bf16 in 4 VGPRs
typedef __attribute__((ext_vector_type(4))) float f32x4;

#define DF 128

__device__ __forceinline__ float bf2f(u32 h) { return __uint_as_float(h << 16); }
__device__ __forceinline__ u16 f2bf(float f) {
  u32 u = __float_as_uint(f);
  u32 r = (u + 0x7fffu + ((u >> 16) & 1u)) >> 16;   // RNE
  return (u16)r;
}
__device__ __forceinline__ u32 pack2(float a, float b) {
  return (u32)f2bf(a) | ((u32)f2bf(b) << 16);
}

// ---------- generic f32 -> bf16 conversion (x, W1, W2) ----------
__global__ void k_cvt_f32_bf16(const float* __restrict__ in, u16* __restrict__ out, int n4) {
  int i = blockIdx.x * blockDim.x + threadIdx.x;
  if (i >= n4) return;
  float4 v = ((const float4*)in)[i];
  ((uint2*)out)[i] = make_uint2(pack2(v.x, v.y), pack2(v.z, v.w));
}

// ---------- CSR build ----------
__global__ void k_hist(const int* __restrict__ dst, int* __restrict__ deg, int E, int N) {
  int e = blockIdx.x * blockDim.x + threadIdx.x;
  if (e < E) { u32 d = (u32)dst[e]; if (d < (u32)N) atomicAdd(&deg[d], 1); }
}

__global__ void k_scan1(const int* __restrict__ deg, int* __restrict__ part,
                        int* __restrict__ bsum, int N) {
  __shared__ int sh[256];
  int t = threadIdx.x, i = blockIdx.x * 256 + t;
  int v = (i < N) ? deg[i] : 0;
  sh[t] = v; __syncthreads();
  for (int o = 1; o < 256; o <<= 1) {
    int tv = (t >= o) ? sh[t - o] : 0;
    __syncthreads();
    sh[t] += tv;
    __syncthreads();
  }
  if (i < N) part[i] = sh[t] - v;            // exclusive
  if (t == 255) bsum[blockIdx.x] = sh[255];  // block total
}

__global__ void k_scan2(int* bsum, int nb) {
  if (blockIdx.x == 0 && threadIdx.x == 0) {
    int run = 0;
    for (int b = 0; b < nb; b++) { int t = bsum[b]; bsum[b] = run; run += t; }
  }
}

__global__ void k_scan3(int* __restrict__ rowptr, const int* __restrict__ bsum,
                        int* __restrict__ cursor, int N, int E) {
  int i = blockIdx.x * blockDim.x + threadIdx.x;
  if (i < N) {
    int v = rowptr[i] + bsum[i >> 8];
    rowptr[i] = v; cursor[i] = v;
  }
  if (i == N) rowptr[N] = E;
}

__global__ void k_scatter(const int* __restrict__ src, const int* __restrict__ dstv,
                          int* __restrict__ cursor, int* __restrict__ adj, int E, int N) {
  int e = blockIdx.x * blockDim.x + threadIdx.x;
  if (e < E) {
    u32 d = (u32)dstv[e];
    if (d < (u32)N) {
      int p = atomicAdd(&cursor[d], 1);
      adj[p] = src[e];
    }
  }
}

// ---------- aggregation with fused BN+ReLU of previous layer ----------
// h' = bn? relu(a*u+c) : u   (elementwise, f32 at load)
// z  = (1+eps)*h'  +  sum_{e:dst==n} relu(h'[src])      (relu∘relu = relu)
// layout: one wave per node; 16 lanes per neighbor row (uint4 = 8 feats/lane),
// 4 neighbor slots (g = lane>>4), edge loop unrolled x2 => 8 gathers in flight.
__global__ void k_aggr(const u16* __restrict__ h, const int* __restrict__ rowptr,
                       const int* __restrict__ adj, const float* __restrict__ epsArr,
                       int layer, const float* __restrict__ bnA,
                       const float* __restrict__ bnC, int useBN,
                       u16* __restrict__ z, int N) {
  int wid = (blockIdx.x * blockDim.x + threadIdx.x) >> 6;
  if (wid >= N) return;
  int lane = threadIdx.x & 63;
  int g = lane >> 4, f = lane & 15;          // neighbor slot, feature group
  const uint4* h4 = (const uint4*)h;

  float av[8], cv[8];
  if (useBN) {
    float4 a0 = *(const float4*)(bnA + f * 8), a1 = *(const float4*)(bnA + f * 8 + 4);
    float4 c0 = *(const float4*)(bnC + f * 8), c1 = *(const float4*)(bnC + f * 8 + 4);
    av[0]=a0.x; av[1]=a0.y; av[2]=a0.z; av[3]=a0.w; av[4]=a1.x; av[5]=a1.y; av[6]=a1.z; av[7]=a1.w;
    cv[0]=c0.x; cv[1]=c0.y; cv[2]=c0.z; cv[3]=c0.w; cv[4]=c1.x; cv[5]=c1.y; cv[6]=c1.z; cv[7]=c1.w;
  }
  float e1 = 1.0f + epsArr[layer];

  float acc[8];
  #pragma unroll
  for (int k = 0; k < 8; k++) acc[k] = 0.0f;

  // self term, group 0 only (counted once after cross-group reduction)
  if (g == 0) {
    uint4 v = h4[(size_t)wid * 16 + f];
    u32 w[4] = {v.x, v.y, v.z, v.w};
    #pragma unroll
    for (int k = 0; k < 8; k++) {
      float hv = bf2f((w[k >> 1] >> ((k & 1) * 16)) & 0xffffu);
      if (useBN) hv = fmaxf(fmaf(av[k], hv, cv[k]), 0.0f);   // inter-layer h has relu
      acc[k] = e1 * hv;
    }
  }

  int b = rowptr[wid], e = rowptr[wid + 1];
  for (int p = b; p < e; p += 8) {
    int i0 = p + g, i1 = p + 4 + g;
    int s0 = (i0 < e) ? adj[i0] : -1;
    int s1 = (i1 < e) ? adj[i1] : -1;
    uint4 v0 = make_uint4(0, 0, 0, 0), v1 = make_uint4(0, 0, 0, 0);
    if (s0 >= 0) v0 = h4[(size_t)s0 * 16 + f];
    if (s1 >= 0) v1 = h4[(size_t)s1 * 16 + f];
    float m0 = (s0 >= 0) ? 1.0f : 0.0f;
    float m1 = (s1 >= 0) ? 1.0f : 0.0f;
    u32 w0[4] = {v0.x, v0.y, v0.z, v0.w};
    u32 w1[4] = {v1.x, v1.y, v1.z, v1.w};
    #pragma unroll
    for (int k = 0; k < 8; k++) {
      float x0 = bf2f((w0[k >> 1] >> ((k & 1) * 16)) & 0xffffu);
      float x1 = bf2f((w1[k >> 1] >> ((k & 1) * 16)) & 0xffffu);
      if (useBN) { x0 = fmaf(av[k], x0, cv[k]); x1 = fmaf(av[k], x1, cv[k]); }
      acc[k] = fmaf(m0, fmaxf(x0, 0.0f), acc[k]);
      acc[k] = fmaf(m1, fmaxf(x1, 0.0f), acc[k]);
    }
  }

  // reduce across the 4 neighbor slots
  #pragma unroll
  for (int k = 0; k < 8; k++) {
    acc[k] += __shfl_xor(acc[k], 16);
    acc[k] += __shfl_xor(acc[k], 32);
  }
  if (g == 0) {
    uint4 o = make_uint4(pack2(acc[0], acc[1]), pack2(acc[2], acc[3]),
                         pack2(acc[4], acc[5]), pack2(acc[6], acc[7]));
    ((uint4*)z)[(size_t)wid * 16 + f] = o;
  }
}

// ---------- GEMM: out[r][c] = sum_k in[r][k] * W[c][k] + bias[c]  (bf16 MFMA) ----------
// optional input transform: in' = relu(a[k]*in + c[k])  (fused BN+ReLU of previous stage)
// accumulates column sum / sumsq of f32 outputs into statS/statQ (valid rows only)
// LDS tiles stored in MFMA fragment order: slot = ((kt*8 + tile)*64 + lane), 16B/lane
__global__ __launch_bounds__(256, 2) void k_gemm(
    const u16* __restrict__ A, const u16* __restrict__ W, const float* __restrict__ bias,
    const float* __restrict__ ain, const float* __restrict__ cin, int trans,
    float* __restrict__ statS, float* __restrict__ statQ,
    u16* __restrict__ out, int Nrows) {
  __shared__ u16 lA[4 * 8 * 64 * 8];  // 32 KB
  __shared__ u16 lB[4 * 8 * 64 * 8];  // 32 KB
  int tid = threadIdx.x;
  int rowBase = blockIdx.x * 128;

  // stage A (z rows) in fragment order
  #pragma unroll
  for (int cc = 0; cc < 8; cc++) {
    int c = tid + cc * 256;
    int lane = c & 63, rt = (c >> 6) & 7, kt = c >> 9;
    int m = lane & 15, quad = lane >> 4;
    int grow = rowBase + rt * 16 + m;
    int gk = kt * 32 + quad * 8;
    uint4 val = make_uint4(0, 0, 0, 0);
    if (grow < Nrows) val = *(const uint4*)(A + (size_t)grow * DF + gk);
    if (trans) {
      float4 av0 = *(const float4*)(ain + gk);
      float4 av1 = *(const float4*)(ain + gk + 4);
      float4 cv0 = *(const float4*)(cin + gk);
      float4 cv1 = *(const float4*)(cin + gk + 4);
      float f0 = fmaxf(fmaf(av0.x, bf2f(val.x & 0xffffu), cv0.x), 0.0f);
      float f1 = fmaxf(fmaf(av0.y, bf2f(val.x >> 16),     cv0.y), 0.0f);
      float f2 = fmaxf(fmaf(av0.z, bf2f(val.y & 0xffffu), cv0.z), 0.0f);
      float f3 = fmaxf(fmaf(av0.w, bf2f(val.y >> 16),     cv0.w), 0.0f);
      float f4 = fmaxf(fmaf(av1.x, bf2f(val.z & 0xffffu), cv1.x), 0.0f);
      float f5 = fmaxf(fmaf(av1.y, bf2f(val.z >> 16),     cv1.y), 0.0f);
      float f6 = fmaxf(fmaf(av1.z, bf2f(val.w & 0xffffu), cv1.z), 0.0f);
      float f7 = fmaxf(fmaf(av1.w, bf2f(val.w >> 16),     cv1.w), 0.0f);
      val = make_uint4(pack2(f0, f1), pack2(f2, f3), pack2(f4, f5), pack2(f6, f7));
    }
    ((uint4*)lA)[c] = val;
  }
  // stage B (W rows, [c][k]) in fragment order
  #pragma unroll
  for (int cc = 0; cc < 8; cc++) {
    int c = tid + cc * 256;
    int lane = c & 63, ct = (c >> 6) & 7, kt = c >> 9;
    int n = lane & 15, quad = lane >> 4;
    ((uint4*)lB)[c] = *(const uint4*)(W + (ct * 16 + n) * DF + kt * 32 + quad * 8);
  }
  __syncthreads();

  int lane = tid & 63, w = tid >> 6;
  int rq = w >> 1, cq = w & 1;  // wave -> 64x64 quadrant
  f32x4 acc[4][4];
  #pragma unroll
  for (int i = 0; i < 4; i++)
    #pragma unroll
    for (int j = 0; j < 4; j++) acc[i][j] = (f32x4){0.f, 0.f, 0.f, 0.f};

  const bf16x8* pA = (const bf16x8*)lA;
  const bf16x8* pB = (const bf16x8*)lB;
  #pragma unroll
  for (int kt = 0; kt < 4; kt++) {
    bf16x8 af[4], bfr[4];
    #pragma unroll
    for (int i = 0; i < 4; i++) af[i] = pA[(kt * 8 + rq * 4 + i) * 64 + lane];
    #pragma unroll
    for (int j = 0; j < 4; j++) bfr[j] = pB[(kt * 8 + cq * 4 + j) * 64 + lane];
    #pragma unroll
    for (int i = 0; i < 4; i++)
      #pragma unroll
      for (int j = 0; j < 4; j++)
        acc[i][j] = __builtin_amdgcn_mfma_f32_16x16x32_bf16(af[i], bfr[j], acc[i][j], 0, 0, 0);
  }

  // epilogue: bias, store bf16, per-column stats
  int mcol = lane & 15, quad = lane >> 4;
  float colS[4] = {0, 0, 0, 0}, colQ[4] = {0, 0, 0, 0};
  #pragma unroll
  for (int j = 0; j < 4; j++) {
    int col = (cq * 4 + j) * 16 + mcol;
    float bv = bias[col];
    #pragma unroll
    for (int i = 0; i < 4; i++) {
      int row0 = rowBase + (rq * 4 + i) * 16 + quad * 4;
      #pragma unroll
      for (int r = 0; r < 4; r++) {
        int row = row0 + r;
        if (row < Nrows) {
          float v = acc[i][j][r] + bv;
          out[(size_t)row * DF + col] = f2bf(v);
          colS[j] += v;
          colQ[j] += v * v;
        }
      }
    }
  }
  #pragma unroll
  for (int j = 0; j < 4; j++) {
    float s = colS[j], q = colQ[j];
    s += __shfl_xor(s, 16); q += __shfl_xor(q, 16);
    s += __shfl_xor(s, 32); q += __shfl_xor(q, 32);
    if (quad == 0) {
      int col = (cq * 4 + j) * 16 + mcol;
      atomicAdd(&statS[col], s);
      atomicAdd(&statQ[col], q);
    }
  }
}

// ---------- finalize BN stats into affine a,c ----------
__global__ void k_finalize(const float* __restrict__ s, const float* __restrict__ q,
                           const float* __restrict__ gamma, const float* __restrict__ beta,
                           float* __restrict__ a, float* __restrict__ c, int Nrows) {
  int t = threadIdx.x;
  if (t < DF) {
    float inv_n = 1.0f / (float)Nrows;
    float mean = s[t] * inv_n;
    float var = fmaxf(q[t] * inv_n - mean * mean, 0.0f);
    float iv = rsqrtf(var + 1e-5f);
    float av = gamma[t] * iv;
    a[t] = av;
    c[t] = beta[t] - mean * av;
  }
}

// ---------- BN apply, f32 out (final layer, no relu) ----------
__global__ void k_bnapply_f32(const u16* __restrict__ u, const float* __restrict__ a,
                              const float* __restrict__ c, float* __restrict__ out, int n8) {
  int i = blockIdx.x * blockDim.x + threadIdx.x;
  if (i >= n8) return;
  int col = (i * 8) & 127;
  float4 a0 = *(const float4*)(a + col), a1v = *(const float4*)(a + col + 4);
  float4 c0 = *(const float4*)(c + col), c1v = *(const float4*)(c + col + 4);
  uint4 v = ((const uint4*)u)[i];
  float4 o0, o1;
  o0.x = fmaf(a0.x, bf2f(v.x & 0xffffu), c0.x);
  o0.y = fmaf(a0.y, bf2f(v.x >> 16),     c0.y);
  o0.z = fmaf(a0.z, bf2f(v.y & 0xffffu), c0.z);
  o0.w = fmaf(a0.w, bf2f(v.y >> 16),     c0.w);
  o1.x = fmaf(a1v.x, bf2f(v.z & 0xffffu), c1v.x);
  o1.y = fmaf(a1v.y, bf2f(v.z >> 16),     c1v.y);
  o1.z = fmaf(a1v.z, bf2f(v.w & 0xffffu), c1v.z);
  o1.w = fmaf(a1v.w, bf2f(v.w >> 16),     c1v.w);
  ((float4*)out)[i * 2] = o0;
  ((float4*)out)[i * 2 + 1] = o1;
}

extern "C" void kernel_launch(void* const* d_in, const int* in_sizes, int n_in,
                              void* d_out, int out_size, void* d_ws, size_t ws_size,
                              hipStream_t stream) {
  const float* x    = (const float*)d_in[0];
  const int*   ei   = (const int*)d_in[1];
  const float* W1   = (const float*)d_in[2];
  const float* b1   = (const float*)d_in[3];
  const float* g1   = (const float*)d_in[4];
  const float* bt1  = (const float*)d_in[5];
  const float* W2   = (const float*)d_in[6];
  const float* b2   = (const float*)d_in[7];
  const float* eps  = (const float*)d_in[8];
  const float* gout = (const float*)d_in[9];
  const float* btout= (const float*)d_in[10];

  int N = in_sizes[0] / DF;
  int E = in_sizes[1] / 2;
  int L = in_sizes[8];

  char* ws = (char*)d_ws;
  size_t off = 0;
  auto alloc = [&](size_t bytes) -> void* {
    void* p = ws + off;
    off += (bytes + 255) & ~(size_t)255;
    return p;
  };
  u16* Xb     = (u16*)alloc((size_t)N * DF * 2);
  u16* bufA   = (u16*)alloc((size_t)N * DF * 2);
  u16* bufB   = (u16*)alloc((size_t)N * DF * 2);
  int* degcur = (int*)alloc((size_t)N * 4);
  int* rowptr = (int*)alloc((size_t)(N + 1) * 4);
  int* adj    = (int*)alloc((size_t)E * 4);
  int* bsum   = (int*)alloc(4096);
  u16* W1b    = (u16*)alloc((size_t)L * DF * DF * 2);
  u16* W2b    = (u16*)alloc((size_t)L * DF * DF * 2);
  float* stats= (float*)alloc((size_t)L * 4 * DF * 4);
  float* coefs= (float*)alloc((size_t)L * 4 * DF * 4);

  hipMemsetAsync(degcur, 0, (size_t)N * 4, stream);
  hipMemsetAsync(stats, 0, (size_t)L * 4 * DF * 4, stream);

  int n4x = N * DF / 4;
  k_cvt_f32_bf16<<<(n4x + 255) / 256, 256, 0, stream>>>(x, Xb, n4x);
  int n4w = L * DF * DF / 4;
  k_cvt_f32_bf16<<<(n4w + 255) / 256, 256, 0, stream>>>(W1, W1b, n4w);
  k_cvt_f32_bf16<<<(n4w + 255) / 256, 256, 0, stream>>>(W2, W2b, n4w);

  const int* srcI = ei;
  const int* dstI = ei + E;
  int nb = (N + 255) / 256;
  k_hist<<<(E + 255) / 256, 256, 0, stream>>>(dstI, degcur, E, N);
  k_scan1<<<nb, 256, 0, stream>>>(degcur, rowptr, bsum, N);
  k_scan2<<<1, 64, 0, stream>>>(bsum, nb);
  k_scan3<<<(N + 256) / 256, 256, 0, stream>>>(rowptr, bsum, degcur, N, E);
  k_scatter<<<(E + 255) / 256, 256, 0, stream>>>(srcI, dstI, degcur, adj, E, N);

  // ping-pong: P = current h source (raw u for l>0, x for l=0)
  u16* P = Xb;
  u16* A = bufA;
  u16* B = bufB;
  int gblocks = (N + 127) / 128;
  int n8 = N * DF / 8;
  float* a2prev = nullptr; float* c2prev = nullptr;
  for (int l = 0; l < L; l++) {
    float* S1 = stats + l * 4 * DF; float* Q1 = S1 + DF; float* S2 = Q1 + DF; float* Q2 = S2 + DF;
    float* a1 = coefs + l * 4 * DF; float* c1 = a1 + DF; float* a2 = c1 + DF; float* c2 = a2 + DF;
    // z = (1+eps)h' + aggr(relu(h')), h' = bn?relu(a*u+c):u        P -> A
    k_aggr<<<(N + 3) / 4, 256, 0, stream>>>(P, rowptr, adj, eps, l,
                                            a2prev, c2prev, a2prev != nullptr, A, N);
    // t = z @ W1^T + b1, stats                                     A -> B
    k_gemm<<<gblocks, 256, 0, stream>>>(A, W1b + l * DF * DF, b1 + l * DF,
                                        nullptr, nullptr, 0, S1, Q1, B, N);
    k_finalize<<<1, 128, 0, stream>>>(S1, Q1, g1 + l * DF, bt1 + l * DF, a1, c1, N);
    // u = relu(BN1(t)) @ W2^T + b2, stats                          B -> A
    k_gemm<<<gblocks, 256, 0, stream>>>(B, W2b + l * DF * DF, b2 + l * DF,
                                        a1, c1, 1, S2, Q2, A, N);
    k_finalize<<<1, 128, 0, stream>>>(S2, Q2, gout + l * DF, btout + l * DF, a2, c2, N);
    a2prev = a2; c2prev = c2;
    P = A;
    u16* t = A; A = B; B = t;
  }
  // final output: BN2(u) in f32, no relu
  k_bnapply_f32<<<(n8 + 255) / 256, 256, 0, stream>>>(P, a2prev, c2prev, (float*)d_out, n8);
}

// Round 3
// 539.837 us; speedup vs baseline: 1.3748x; 1.2186x over previous
//
#include <hip/hip_runtime.h>

typedef unsigned int u32;
typedef unsigned short u16;
typedef __attribute__((ext_vector_type(8))) short bf16x8;   // 8 bf16 in 4 VGPRs
typedef __attribute__((ext_vector_type(4))) float f32x4;

#define DF 128
#define NBUCK 256          // max buckets (dst >> 9), N=100k -> 196 used
#define BUCK_SHIFT 9
#define BUCK_SIZE 512
#define P2_CHUNK 4096      // 16 edges per thread, 256 threads

__device__ __forceinline__ float bf2f(u32 h) { return __uint_as_float(h << 16); }
__device__ __forceinline__ u16 f2bf(float f) {
  u32 u = __float_as_uint(f);
  u32 r = (u + 0x7fffu + ((u >> 16) & 1u)) >> 16;   // RNE
  return (u16)r;
}
__device__ __forceinline__ u32 pack2(float a, float b) {
  return (u32)f2bf(a) | ((u32)f2bf(b) << 16);
}

// ---------- generic f32 -> bf16 conversion (x, W1, W2) ----------
__global__ void k_cvt_f32_bf16(const float* __restrict__ in, u16* __restrict__ out, int n4) {
  int i = blockIdx.x * blockDim.x + threadIdx.x;
  if (i >= n4) return;
  float4 v = ((const float4*)in)[i];
  ((uint2*)out)[i] = make_uint2(pack2(v.x, v.y), pack2(v.z, v.w));
}

// ---------- CSR build via bucketed counting sort ----------
// P1: per-block LDS histogram of dst>>BUCK_SHIFT
__global__ __launch_bounds__(256) void k_p1(const int* __restrict__ dst,
                                            int* __restrict__ bucketCount, int E) {
  __shared__ int h[NBUCK];
  int t = threadIdx.x;
  h[t] = 0;
  __syncthreads();
  for (int e = blockIdx.x * 256 + t; e < E; e += gridDim.x * 256)
    atomicAdd(&h[((u32)dst[e]) >> BUCK_SHIFT], 1);
  __syncthreads();
  if (h[t]) atomicAdd(&bucketCount[t], h[t]);
}

// Pscan: one block scans 256 bucket counts -> bucketStart / bucketCursor
__global__ __launch_bounds__(256) void k_pscan(const int* __restrict__ bucketCount,
                                               int* __restrict__ bucketStart,
                                               int* __restrict__ bucketCursor,
                                               int* __restrict__ rowptr, int N, int E) {
  __shared__ int sh[NBUCK];
  int t = threadIdx.x;
  int c = bucketCount[t];
  sh[t] = c;
  __syncthreads();
  for (int o = 1; o < 256; o <<= 1) {
    int v = (t >= o) ? sh[t - o] : 0;
    __syncthreads();
    sh[t] += v;
    __syncthreads();
  }
  int excl = sh[t] - c;
  bucketStart[t] = excl;
  bucketCursor[t] = excl;
  if (t == 255) { bucketStart[256] = sh[255]; rowptr[N] = E; }
}

// P2: partition edges into bucket-contiguous array (LDS-staged, run-contiguous writes)
__global__ __launch_bounds__(256) void k_p2(const int* __restrict__ src,
                                            const int* __restrict__ dst,
                                            int* __restrict__ bucketCursor,
                                            uint2* __restrict__ part, int E) {
  __shared__ int h[NBUCK], hs[NBUCK], base[NBUCK];
  __shared__ int total;
  __shared__ uint2 buf[P2_CHUNK];
  int t = threadIdx.x;
  int e0 = blockIdx.x * P2_CHUNK;
  h[t] = 0;
  __syncthreads();
  int myb[16], myr[16];
  uint2 mye[16];
  #pragma unroll
  for (int k = 0; k < 16; k++) {
    int e = e0 + k * 256 + t;
    myb[k] = -1;
    if (e < E) {
      int s = src[e], d = dst[e];
      mye[k] = make_uint2((u32)s, (u32)d);
      myb[k] = ((u32)d) >> BUCK_SHIFT;
      myr[k] = atomicAdd(&h[myb[k]], 1);
    }
  }
  __syncthreads();
  int hc = h[t];
  hs[t] = hc;
  __syncthreads();
  for (int o = 1; o < 256; o <<= 1) {
    int v = (t >= o) ? hs[t - o] : 0;
    __syncthreads();
    hs[t] += v;
    __syncthreads();
  }
  if (t == 255) total = hs[255];
  int excl = hs[t] - hc;
  base[t] = hc ? atomicAdd(&bucketCursor[t], hc) : 0;
  __syncthreads();
  hs[t] = excl;
  __syncthreads();
  #pragma unroll
  for (int k = 0; k < 16; k++)
    if (myb[k] >= 0) buf[hs[myb[k]] + myr[k]] = mye[k];
  __syncthreads();
  int tot = total;
  for (int i = t; i < tot; i += 256) {
    uint2 ed = buf[i];
    int b = ed.y >> BUCK_SHIFT;
    part[base[b] + (i - hs[b])] = ed;
  }
}

// P3: one block per bucket: LDS degree hist + scan -> rowptr, LDS-cursor scatter -> adj
__global__ __launch_bounds__(256) void k_p3(const uint2* __restrict__ part,
                                            const int* __restrict__ bucketStart,
                                            int* __restrict__ rowptr,
                                            int* __restrict__ adj, int N) {
  __shared__ int deg[BUCK_SIZE], cur[BUCK_SIZE], psum[256];
  int b = blockIdx.x, t = threadIdx.x;
  int nodeBase = b << BUCK_SHIFT;
  int eb = bucketStart[b], ee = bucketStart[b + 1];
  deg[t] = 0; deg[t + 256] = 0;
  __syncthreads();
  for (int e = eb + t; e < ee; e += 256)
    atomicAdd(&deg[(int)part[e].y - nodeBase], 1);
  __syncthreads();
  int a0 = deg[2 * t], a1 = deg[2 * t + 1];
  psum[t] = a0 + a1;
  __syncthreads();
  for (int o = 1; o < 256; o <<= 1) {
    int v = (t >= o) ? psum[t - o] : 0;
    __syncthreads();
    psum[t] += v;
    __syncthreads();
  }
  int basep = psum[t] - (a0 + a1);
  int p0 = eb + basep, p1 = eb + basep + a0;
  cur[2 * t] = p0; cur[2 * t + 1] = p1;
  int n0 = nodeBase + 2 * t, n1 = nodeBase + 2 * t + 1;
  if (n0 < N) rowptr[n0] = p0;
  if (n1 < N) rowptr[n1] = p1;
  __syncthreads();
  for (int e = eb + t; e < ee; e += 256) {
    uint2 ed = part[e];
    int pos = atomicAdd(&cur[(int)ed.y - nodeBase], 1);
    adj[pos] = (int)ed.x;
  }
}

// ---------- aggregation with fused BN+ReLU of previous layer ----------
// h' = bn? relu(a*u+c) : u   (elementwise, f32 at load)
// z  = (1+eps)*h'  +  sum_{e:dst==n} relu(h'[src])      (relu∘relu = relu)
// layout: one wave per node; 16 lanes per neighbor row (uint4 = 8 feats/lane),
// 4 neighbor slots (g = lane>>4), edge loop unrolled x2 => 8 gathers in flight.
__global__ void k_aggr(const u16* __restrict__ h, const int* __restrict__ rowptr,
                       const int* __restrict__ adj, const float* __restrict__ epsArr,
                       int layer, const float* __restrict__ bnA,
                       const float* __restrict__ bnC, int useBN,
                       u16* __restrict__ z, int N) {
  int wid = (blockIdx.x * blockDim.x + threadIdx.x) >> 6;
  if (wid >= N) return;
  int lane = threadIdx.x & 63;
  int g = lane >> 4, f = lane & 15;          // neighbor slot, feature group
  const uint4* h4 = (const uint4*)h;

  float av[8], cv[8];
  if (useBN) {
    float4 a0 = *(const float4*)(bnA + f * 8), a1 = *(const float4*)(bnA + f * 8 + 4);
    float4 c0 = *(const float4*)(bnC + f * 8), c1 = *(const float4*)(bnC + f * 8 + 4);
    av[0]=a0.x; av[1]=a0.y; av[2]=a0.z; av[3]=a0.w; av[4]=a1.x; av[5]=a1.y; av[6]=a1.z; av[7]=a1.w;
    cv[0]=c0.x; cv[1]=c0.y; cv[2]=c0.z; cv[3]=c0.w; cv[4]=c1.x; cv[5]=c1.y; cv[6]=c1.z; cv[7]=c1.w;
  }
  float e1 = 1.0f + epsArr[layer];

  float acc[8];
  #pragma unroll
  for (int k = 0; k < 8; k++) acc[k] = 0.0f;

  // self term, group 0 only (counted once after cross-group reduction)
  if (g == 0) {
    uint4 v = h4[(size_t)wid * 16 + f];
    u32 w[4] = {v.x, v.y, v.z, v.w};
    #pragma unroll
    for (int k = 0; k < 8; k++) {
      float hv = bf2f((w[k >> 1] >> ((k & 1) * 16)) & 0xffffu);
      if (useBN) hv = fmaxf(fmaf(av[k], hv, cv[k]), 0.0f);   // inter-layer h has relu
      acc[k] = e1 * hv;
    }
  }

  int b = rowptr[wid], e = rowptr[wid + 1];
  for (int p = b; p < e; p += 8) {
    int i0 = p + g, i1 = p + 4 + g;
    int s0 = (i0 < e) ? adj[i0] : -1;
    int s1 = (i1 < e) ? adj[i1] : -1;
    uint4 v0 = make_uint4(0, 0, 0, 0), v1 = make_uint4(0, 0, 0, 0);
    if (s0 >= 0) v0 = h4[(size_t)s0 * 16 + f];
    if (s1 >= 0) v1 = h4[(size_t)s1 * 16 + f];
    float m0 = (s0 >= 0) ? 1.0f : 0.0f;
    float m1 = (s1 >= 0) ? 1.0f : 0.0f;
    u32 w0[4] = {v0.x, v0.y, v0.z, v0.w};
    u32 w1[4] = {v1.x, v1.y, v1.z, v1.w};
    #pragma unroll
    for (int k = 0; k < 8; k++) {
      float x0 = bf2f((w0[k >> 1] >> ((k & 1) * 16)) & 0xffffu);
      float x1 = bf2f((w1[k >> 1] >> ((k & 1) * 16)) & 0xffffu);
      if (useBN) { x0 = fmaf(av[k], x0, cv[k]); x1 = fmaf(av[k], x1, cv[k]); }
      acc[k] = fmaf(m0, fmaxf(x0, 0.0f), acc[k]);
      acc[k] = fmaf(m1, fmaxf(x1, 0.0f), acc[k]);
    }
  }

  // reduce across the 4 neighbor slots
  #pragma unroll
  for (int k = 0; k < 8; k++) {
    acc[k] += __shfl_xor(acc[k], 16);
    acc[k] += __shfl_xor(acc[k], 32);
  }
  if (g == 0) {
    uint4 o = make_uint4(pack2(acc[0], acc[1]), pack2(acc[2], acc[3]),
                         pack2(acc[4], acc[5]), pack2(acc[6], acc[7]));
    ((uint4*)z)[(size_t)wid * 16 + f] = o;
  }
}

// ---------- GEMM: out[r][c] = sum_k in[r][k] * W[c][k] + bias[c]  (bf16 MFMA) ----------
// optional input transform: in' = relu(a[k]*in + c[k])  (fused BN+ReLU of previous stage)
// accumulates column sum / sumsq of f32 outputs into statS/statQ (valid rows only)
// LDS tiles stored in MFMA fragment order: slot = ((kt*8 + tile)*64 + lane), 16B/lane
__global__ __launch_bounds__(256, 2) void k_gemm(
    const u16* __restrict__ A, const u16* __restrict__ W, const float* __restrict__ bias,
    const float* __restrict__ ain, const float* __restrict__ cin, int trans,
    float* __restrict__ statS, float* __restrict__ statQ,
    u16* __restrict__ out, int Nrows) {
  __shared__ u16 lA[4 * 8 * 64 * 8];  // 32 KB
  __shared__ u16 lB[4 * 8 * 64 * 8];  // 32 KB
  int tid = threadIdx.x;
  int rowBase = blockIdx.x * 128;

  // stage A (z rows) in fragment order
  #pragma unroll
  for (int cc = 0; cc < 8; cc++) {
    int c = tid + cc * 256;
    int lane = c & 63, rt = (c >> 6) & 7, kt = c >> 9;
    int m = lane & 15, quad = lane >> 4;
    int grow = rowBase + rt * 16 + m;
    int gk = kt * 32 + quad * 8;
    uint4 val = make_uint4(0, 0, 0, 0);
    if (grow < Nrows) val = *(const uint4*)(A + (size_t)grow * DF + gk);
    if (trans) {
      float4 av0 = *(const float4*)(ain + gk);
      float4 av1 = *(const float4*)(ain + gk + 4);
      float4 cv0 = *(const float4*)(cin + gk);
      float4 cv1 = *(const float4*)(cin + gk + 4);
      float f0 = fmaxf(fmaf(av0.x, bf2f(val.x & 0xffffu), cv0.x), 0.0f);
      float f1 = fmaxf(fmaf(av0.y, bf2f(val.x >> 16),     cv0.y), 0.0f);
      float f2 = fmaxf(fmaf(av0.z, bf2f(val.y & 0xffffu), cv0.z), 0.0f);
      float f3 = fmaxf(fmaf(av0.w, bf2f(val.y >> 16),     cv0.w), 0.0f);
      float f4 = fmaxf(fmaf(av1.x, bf2f(val.z & 0xffffu), cv1.x), 0.0f);
      float f5 = fmaxf(fmaf(av1.y, bf2f(val.z >> 16),     cv1.y), 0.0f);
      float f6 = fmaxf(fmaf(av1.z, bf2f(val.w & 0xffffu), cv1.z), 0.0f);
      float f7 = fmaxf(fmaf(av1.w, bf2f(val.w >> 16),     cv1.w), 0.0f);
      val = make_uint4(pack2(f0, f1), pack2(f2, f3), pack2(f4, f5), pack2(f6, f7));
    }
    ((uint4*)lA)[c] = val;
  }
  // stage B (W rows, [c][k]) in fragment order
  #pragma unroll
  for (int cc = 0; cc < 8; cc++) {
    int c = tid + cc * 256;
    int lane = c & 63, ct = (c >> 6) & 7, kt = c >> 9;
    int n = lane & 15, quad = lane >> 4;
    ((uint4*)lB)[c] = *(const uint4*)(W + (ct * 16 + n) * DF + kt * 32 + quad * 8);
  }
  __syncthreads();

  int lane = tid & 63, w = tid >> 6;
  int rq = w >> 1, cq = w & 1;  // wave -> 64x64 quadrant
  f32x4 acc[4][4];
  #pragma unroll
  for (int i = 0; i < 4; i++)
    #pragma unroll
    for (int j = 0; j < 4; j++) acc[i][j] = (f32x4){0.f, 0.f, 0.f, 0.f};

  const bf16x8* pA = (const bf16x8*)lA;
  const bf16x8* pB = (const bf16x8*)lB;
  #pragma unroll
  for (int kt = 0; kt < 4; kt++) {
    bf16x8 af[4], bfr[4];
    #pragma unroll
    for (int i = 0; i < 4; i++) af[i] = pA[(kt * 8 + rq * 4 + i) * 64 + lane];
    #pragma unroll
    for (int j = 0; j < 4; j++) bfr[j] = pB[(kt * 8 + cq * 4 + j) * 64 + lane];
    #pragma unroll
    for (int i = 0; i < 4; i++)
      #pragma unroll
      for (int j = 0; j < 4; j++)
        acc[i][j] = __builtin_amdgcn_mfma_f32_16x16x32_bf16(af[i], bfr[j], acc[i][j], 0, 0, 0);
  }

  // epilogue: bias, store bf16, per-column stats
  int mcol = lane & 15, quad = lane >> 4;
  float colS[4] = {0, 0, 0, 0}, colQ[4] = {0, 0, 0, 0};
  #pragma unroll
  for (int j = 0; j < 4; j++) {
    int col = (cq * 4 + j) * 16 + mcol;
    float bv = bias[col];
    #pragma unroll
    for (int i = 0; i < 4; i++) {
      int row0 = rowBase + (rq * 4 + i) * 16 + quad * 4;
      #pragma unroll
      for (int r = 0; r < 4; r++) {
        int row = row0 + r;
        if (row < Nrows) {
          float v = acc[i][j][r] + bv;
          out[(size_t)row * DF + col] = f2bf(v);
          colS[j] += v;
          colQ[j] += v * v;
        }
      }
    }
  }
  #pragma unroll
  for (int j = 0; j < 4; j++) {
    float s = colS[j], q = colQ[j];
    s += __shfl_xor(s, 16); q += __shfl_xor(q, 16);
    s += __shfl_xor(s, 32); q += __shfl_xor(q, 32);
    if (quad == 0) {
      int col = (cq * 4 + j) * 16 + mcol;
      atomicAdd(&statS[col], s);
      atomicAdd(&statQ[col], q);
    }
  }
}

// ---------- finalize BN stats into affine a,c ----------
__global__ void k_finalize(const float* __restrict__ s, const float* __restrict__ q,
                           const float* __restrict__ gamma, const float* __restrict__ beta,
                           float* __restrict__ a, float* __restrict__ c, int Nrows) {
  int t = threadIdx.x;
  if (t < DF) {
    float inv_n = 1.0f / (float)Nrows;
    float mean = s[t] * inv_n;
    float var = fmaxf(q[t] * inv_n - mean * mean, 0.0f);
    float iv = rsqrtf(var + 1e-5f);
    float av = gamma[t] * iv;
    a[t] = av;
    c[t] = beta[t] - mean * av;
  }
}

// ---------- BN apply, f32 out (final layer, no relu) ----------
__global__ void k_bnapply_f32(const u16* __restrict__ u, const float* __restrict__ a,
                              const float* __restrict__ c, float* __restrict__ out, int n8) {
  int i = blockIdx.x * blockDim.x + threadIdx.x;
  if (i >= n8) return;
  int col = (i * 8) & 127;
  float4 a0 = *(const float4*)(a + col), a1v = *(const float4*)(a + col + 4);
  float4 c0 = *(const float4*)(c + col), c1v = *(const float4*)(c + col + 4);
  uint4 v = ((const uint4*)u)[i];
  float4 o0, o1;
  o0.x = fmaf(a0.x, bf2f(v.x & 0xffffu), c0.x);
  o0.y = fmaf(a0.y, bf2f(v.x >> 16),     c0.y);
  o0.z = fmaf(a0.z, bf2f(v.y & 0xffffu), c0.z);
  o0.w = fmaf(a0.w, bf2f(v.y >> 16),     c0.w);
  o1.x = fmaf(a1v.x, bf2f(v.z & 0xffffu), c1v.x);
  o1.y = fmaf(a1v.y, bf2f(v.z >> 16),     c1v.y);
  o1.z = fmaf(a1v.z, bf2f(v.w & 0xffffu), c1v.z);
  o1.w = fmaf(a1v.w, bf2f(v.w >> 16),     c1v.w);
  ((float4*)out)[i * 2] = o0;
  ((float4*)out)[i * 2 + 1] = o1;
}

extern "C" void kernel_launch(void* const* d_in, const int* in_sizes, int n_in,
                              void* d_out, int out_size, void* d_ws, size_t ws_size,
                              hipStream_t stream) {
  const float* x    = (const float*)d_in[0];
  const int*   ei   = (const int*)d_in[1];
  const float* W1   = (const float*)d_in[2];
  const float* b1   = (const float*)d_in[3];
  const float* g1   = (const float*)d_in[4];
  const float* bt1  = (const float*)d_in[5];
  const float* W2   = (const float*)d_in[6];
  const float* b2   = (const float*)d_in[7];
  const float* eps  = (const float*)d_in[8];
  const float* gout = (const float*)d_in[9];
  const float* btout= (const float*)d_in[10];

  int N = in_sizes[0] / DF;
  int E = in_sizes[1] / 2;
  int L = in_sizes[8];

  char* ws = (char*)d_ws;
  size_t off = 0;
  auto alloc = [&](size_t bytes) -> void* {
    void* p = ws + off;
    off += (bytes + 255) & ~(size_t)255;
    return p;
  };
  u16* Xb     = (u16*)alloc((size_t)N * DF * 2);
  u16* bufA   = (u16*)alloc((size_t)N * DF * 2);
  u16* bufB   = (u16*)alloc((size_t)N * DF * 2);
  int* rowptr = (int*)alloc((size_t)(N + 1) * 4);
  int* adj    = (int*)alloc((size_t)E * 4);
  uint2* part = (uint2*)alloc((size_t)E * 8);
  int* bCount = (int*)alloc(NBUCK * 4);
  int* bStart = (int*)alloc((NBUCK + 1) * 4);
  int* bCur   = (int*)alloc(NBUCK * 4);
  u16* W1b    = (u16*)alloc((size_t)L * DF * DF * 2);
  u16* W2b    = (u16*)alloc((size_t)L * DF * DF * 2);
  float* stats= (float*)alloc((size_t)L * 4 * DF * 4);
  float* coefs= (float*)alloc((size_t)L * 4 * DF * 4);

  hipMemsetAsync(bCount, 0, NBUCK * 4, stream);
  hipMemsetAsync(stats, 0, (size_t)L * 4 * DF * 4, stream);

  int n4x = N * DF / 4;
  k_cvt_f32_bf16<<<(n4x + 255) / 256, 256, 0, stream>>>(x, Xb, n4x);
  int n4w = L * DF * DF / 4;
  k_cvt_f32_bf16<<<(n4w + 255) / 256, 256, 0, stream>>>(W1, W1b, n4w);
  k_cvt_f32_bf16<<<(n4w + 255) / 256, 256, 0, stream>>>(W2, W2b, n4w);

  const int* srcI = ei;
  const int* dstI = ei + E;
  int nbuckets = (N + BUCK_SIZE - 1) >> BUCK_SHIFT;
  k_p1<<<512, 256, 0, stream>>>(dstI, bCount, E);
  k_pscan<<<1, 256, 0, stream>>>(bCount, bStart, bCur, rowptr, N, E);
  k_p2<<<(E + P2_CHUNK - 1) / P2_CHUNK, 256, 0, stream>>>(srcI, dstI, bCur, part, E);
  k_p3<<<nbuckets, 256, 0, stream>>>(part, bStart, rowptr, adj, N);

  // ping-pong: P = current h source (raw u for l>0, x for l=0)
  u16* P = Xb;
  u16* A = bufA;
  u16* B = bufB;
  int gblocks = (N + 127) / 128;
  int n8 = N * DF / 8;
  float* a2prev = nullptr; float* c2prev = nullptr;
  for (int l = 0; l < L; l++) {
    float* S1 = stats + l * 4 * DF; float* Q1 = S1 + DF; float* S2 = Q1 + DF; float* Q2 = S2 + DF;
    float* a1 = coefs + l * 4 * DF; float* c1 = a1 + DF; float* a2 = c1 + DF; float* c2 = a2 + DF;
    // z = (1+eps)h' + aggr(relu(h')), h' = bn?relu(a*u+c):u        P -> A
    k_aggr<<<(N + 3) / 4, 256, 0, stream>>>(P, rowptr, adj, eps, l,
                                            a2prev, c2prev, a2prev != nullptr, A, N);
    // t = z @ W1^T + b1, stats                                     A -> B
    k_gemm<<<gblocks, 256, 0, stream>>>(A, W1b + l * DF * DF, b1 + l * DF,
                                        nullptr, nullptr, 0, S1, Q1, B, N);
    k_finalize<<<1, 128, 0, stream>>>(S1, Q1, g1 + l * DF, bt1 + l * DF, a1, c1, N);
    // u = relu(BN1(t)) @ W2^T + b2, stats                          B -> A
    k_gemm<<<gblocks, 256, 0, stream>>>(B, W2b + l * DF * DF, b2 + l * DF,
                                        a1, c1, 1, S2, Q2, A, N);
    k_finalize<<<1, 128, 0, stream>>>(S2, Q2, gout + l * DF, btout + l * DF, a2, c2, N);
    a2prev = a2; c2prev = c2;
    P = A;
    u16* t = A; A = B; B = t;
  }
  // final output: BN2(u) in f32, no relu
  k_bnapply_f32<<<(n8 + 255) / 256, 256, 0, stream>>>(P, a2prev, c2prev, (float*)d_out, n8);
}

// Round 4
// 436.906 us; speedup vs baseline: 1.6987x; 1.2356x over previous
//
#include <hip/hip_runtime.h>

typedef unsigned int u32;
typedef unsigned short u16;
typedef __attribute__((ext_vector_type(8))) short bf16x8;   // 8 bf16 in 4 VGPRs
typedef __attribute__((ext_vector_type(4))) float f32x4;

#define DF 128
#define NBUCK 256          // max buckets (dst >> 9), N=100k -> 196 used
#define BUCK_SHIFT 9
#define BUCK_SIZE 512
#define P2_CHUNK 4096      // 16 edges per thread, 256 threads
#define NCOPY 16           // stat atomic spreading factor
#define STATW (NCOPY * DF)

__device__ __forceinline__ float bf2f(u32 h) { return __uint_as_float(h << 16); }
__device__ __forceinline__ u16 f2bf(float f) {
  u32 u = __float_as_uint(f);
  u32 r = (u + 0x7fffu + ((u >> 16) & 1u)) >> 16;   // RNE
  return (u16)r;
}
__device__ __forceinline__ u32 pack2(float a, float b) {
  return (u32)f2bf(a) | ((u32)f2bf(b) << 16);
}

// ---------- generic f32 -> bf16 conversion (x, W1, W2) ----------
__global__ void k_cvt_f32_bf16(const float* __restrict__ in, u16* __restrict__ out, int n4) {
  int i = blockIdx.x * blockDim.x + threadIdx.x;
  if (i >= n4) return;
  float4 v = ((const float4*)in)[i];
  ((uint2*)out)[i] = make_uint2(pack2(v.x, v.y), pack2(v.z, v.w));
}

// ---------- CSR build via bucketed counting sort ----------
__global__ __launch_bounds__(256) void k_p1(const int* __restrict__ dst,
                                            int* __restrict__ bucketCount, int E) {
  __shared__ int h[NBUCK];
  int t = threadIdx.x;
  h[t] = 0;
  __syncthreads();
  for (int e = blockIdx.x * 256 + t; e < E; e += gridDim.x * 256)
    atomicAdd(&h[((u32)dst[e]) >> BUCK_SHIFT], 1);
  __syncthreads();
  if (h[t]) atomicAdd(&bucketCount[t], h[t]);
}

__global__ __launch_bounds__(256) void k_pscan(const int* __restrict__ bucketCount,
                                               int* __restrict__ bucketStart,
                                               int* __restrict__ bucketCursor,
                                               int* __restrict__ rowptr, int N, int E) {
  __shared__ int sh[NBUCK];
  int t = threadIdx.x;
  int c = bucketCount[t];
  sh[t] = c;
  __syncthreads();
  for (int o = 1; o < 256; o <<= 1) {
    int v = (t >= o) ? sh[t - o] : 0;
    __syncthreads();
    sh[t] += v;
    __syncthreads();
  }
  int excl = sh[t] - c;
  bucketStart[t] = excl;
  bucketCursor[t] = excl;
  if (t == 255) { bucketStart[256] = sh[255]; rowptr[N] = E; }
}

__global__ __launch_bounds__(256) void k_p2(const int* __restrict__ src,
                                            const int* __restrict__ dst,
                                            int* __restrict__ bucketCursor,
                                            uint2* __restrict__ part, int E) {
  __shared__ int h[NBUCK], hs[NBUCK], base[NBUCK];
  __shared__ int total;
  __shared__ uint2 buf[P2_CHUNK];
  int t = threadIdx.x;
  int e0 = blockIdx.x * P2_CHUNK;
  h[t] = 0;
  __syncthreads();
  int myb[16], myr[16];
  uint2 mye[16];
  #pragma unroll
  for (int k = 0; k < 16; k++) {
    int e = e0 + k * 256 + t;
    myb[k] = -1;
    if (e < E) {
      int s = src[e], d = dst[e];
      mye[k] = make_uint2((u32)s, (u32)d);
      myb[k] = ((u32)d) >> BUCK_SHIFT;
      myr[k] = atomicAdd(&h[myb[k]], 1);
    }
  }
  __syncthreads();
  int hc = h[t];
  hs[t] = hc;
  __syncthreads();
  for (int o = 1; o < 256; o <<= 1) {
    int v = (t >= o) ? hs[t - o] : 0;
    __syncthreads();
    hs[t] += v;
    __syncthreads();
  }
  if (t == 255) total = hs[255];
  int excl = hs[t] - hc;
  base[t] = hc ? atomicAdd(&bucketCursor[t], hc) : 0;
  __syncthreads();
  hs[t] = excl;
  __syncthreads();
  #pragma unroll
  for (int k = 0; k < 16; k++)
    if (myb[k] >= 0) buf[hs[myb[k]] + myr[k]] = mye[k];
  __syncthreads();
  int tot = total;
  for (int i = t; i < tot; i += 256) {
    uint2 ed = buf[i];
    int b = ed.y >> BUCK_SHIFT;
    part[base[b] + (i - hs[b])] = ed;
  }
}

__global__ __launch_bounds__(256) void k_p3(const uint2* __restrict__ part,
                                            const int* __restrict__ bucketStart,
                                            int* __restrict__ rowptr,
                                            int* __restrict__ adj, int N) {
  __shared__ int deg[BUCK_SIZE], cur[BUCK_SIZE], psum[256];
  int b = blockIdx.x, t = threadIdx.x;
  int nodeBase = b << BUCK_SHIFT;
  int eb = bucketStart[b], ee = bucketStart[b + 1];
  deg[t] = 0; deg[t + 256] = 0;
  __syncthreads();
  for (int e = eb + t; e < ee; e += 256)
    atomicAdd(&deg[(int)part[e].y - nodeBase], 1);
  __syncthreads();
  int a0 = deg[2 * t], a1 = deg[2 * t + 1];
  psum[t] = a0 + a1;
  __syncthreads();
  for (int o = 1; o < 256; o <<= 1) {
    int v = (t >= o) ? psum[t - o] : 0;
    __syncthreads();
    psum[t] += v;
    __syncthreads();
  }
  int basep = psum[t] - (a0 + a1);
  int p0 = eb + basep, p1 = eb + basep + a0;
  cur[2 * t] = p0; cur[2 * t + 1] = p1;
  int n0 = nodeBase + 2 * t, n1 = nodeBase + 2 * t + 1;
  if (n0 < N) rowptr[n0] = p0;
  if (n1 < N) rowptr[n1] = p1;
  __syncthreads();
  for (int e = eb + t; e < ee; e += 256) {
    uint2 ed = part[e];
    int pos = atomicAdd(&cur[(int)ed.y - nodeBase], 1);
    adj[pos] = (int)ed.x;
  }
}

// ---------- aggregation: pure bf16 gather-sum ----------
// z = (1+eps)*hself[n] + sum_{e:dst==n} msg(hmsg[src]),  msg = doRelu? relu(.) : identity
// (inter-layer H is stored post-BN+ReLU, so msg is identity for l>0; l=0 needs relu)
// one wave per node; 16 lanes per neighbor row (uint4 = 8 feats/lane), 2x unrolled.
__global__ void k_aggr(const u16* __restrict__ hself, const u16* __restrict__ hmsg,
                       const int* __restrict__ rowptr, const int* __restrict__ adj,
                       const float* __restrict__ epsArr, int layer, int doRelu,
                       u16* __restrict__ z, int N) {
  int wid = (blockIdx.x * blockDim.x + threadIdx.x) >> 6;
  if (wid >= N) return;
  int lane = threadIdx.x & 63;
  int g = lane >> 4, f = lane & 15;          // neighbor slot, feature group
  const uint4* hs4 = (const uint4*)hself;
  const uint4* hm4 = (const uint4*)hmsg;
  float e1 = 1.0f + epsArr[layer];

  float acc[8];
  #pragma unroll
  for (int k = 0; k < 8; k++) acc[k] = 0.0f;

  // self term, group 0 only (no relu on self)
  if (g == 0) {
    uint4 v = hs4[(size_t)wid * 16 + f];
    u32 w[4] = {v.x, v.y, v.z, v.w};
    #pragma unroll
    for (int k = 0; k < 4; k++) {
      acc[2 * k]     = e1 * __uint_as_float(w[k] << 16);
      acc[2 * k + 1] = e1 * __uint_as_float(w[k] & 0xffff0000u);
    }
  }

  int b = rowptr[wid], e = rowptr[wid + 1];
  for (int p = b; p < e; p += 8) {
    int i0 = p + g, i1 = p + 4 + g;
    uint4 v0 = make_uint4(0, 0, 0, 0), v1 = make_uint4(0, 0, 0, 0);
    if (i0 < e) v0 = hm4[(size_t)(u32)adj[i0] * 16 + f];
    if (i1 < e) v1 = hm4[(size_t)(u32)adj[i1] * 16 + f];
    u32 w0[4] = {v0.x, v0.y, v0.z, v0.w};
    u32 w1[4] = {v1.x, v1.y, v1.z, v1.w};
    if (doRelu) {
      // packed bf16 relu: zero each negative 16-bit half
      #pragma unroll
      for (int k = 0; k < 4; k++) {
        u32 a = w0[k];
        if (a & 0x8000u)     a &= 0xffff0000u;
        if (a & 0x80000000u) a &= 0x0000ffffu;
        w0[k] = a;
        u32 bq = w1[k];
        if (bq & 0x8000u)     bq &= 0xffff0000u;
        if (bq & 0x80000000u) bq &= 0x0000ffffu;
        w1[k] = bq;
      }
    }
    #pragma unroll
    for (int k = 0; k < 4; k++) {
      acc[2 * k]     += __uint_as_float(w0[k] << 16);
      acc[2 * k + 1] += __uint_as_float(w0[k] & 0xffff0000u);
      acc[2 * k]     += __uint_as_float(w1[k] << 16);
      acc[2 * k + 1] += __uint_as_float(w1[k] & 0xffff0000u);
    }
  }

  // reduce across the 4 neighbor slots
  #pragma unroll
  for (int k = 0; k < 8; k++) {
    acc[k] += __shfl_xor(acc[k], 16);
    acc[k] += __shfl_xor(acc[k], 32);
  }
  if (g == 0) {
    uint4 o = make_uint4(pack2(acc[0], acc[1]), pack2(acc[2], acc[3]),
                         pack2(acc[4], acc[5]), pack2(acc[6], acc[7]));
    ((uint4*)z)[(size_t)wid * 16 + f] = o;
  }
}

// ---------- GEMM: out[r][c] = sum_k in[r][k] * W[c][k] + bias[c]  (bf16 MFMA) ----------
// optional input transform: in' = relu(a[k]*in + c[k])  (fused BN+ReLU of previous stage)
// stats: per-wave shfl reduce, then atomics spread over NCOPY copies (blockIdx&15)
__global__ __launch_bounds__(256, 2) void k_gemm(
    const u16* __restrict__ A, const u16* __restrict__ W, const float* __restrict__ bias,
    const float* __restrict__ ain, const float* __restrict__ cin, int trans,
    float* __restrict__ statS, float* __restrict__ statQ,
    u16* __restrict__ out, int Nrows) {
  __shared__ u16 lA[4 * 8 * 64 * 8];  // 32 KB
  __shared__ u16 lB[4 * 8 * 64 * 8];  // 32 KB
  int tid = threadIdx.x;
  int rowBase = blockIdx.x * 128;

  // stage A (z rows) in fragment order
  #pragma unroll
  for (int cc = 0; cc < 8; cc++) {
    int c = tid + cc * 256;
    int lane = c & 63, rt = (c >> 6) & 7, kt = c >> 9;
    int m = lane & 15, quad = lane >> 4;
    int grow = rowBase + rt * 16 + m;
    int gk = kt * 32 + quad * 8;
    uint4 val = make_uint4(0, 0, 0, 0);
    if (grow < Nrows) val = *(const uint4*)(A + (size_t)grow * DF + gk);
    if (trans) {
      float4 av0 = *(const float4*)(ain + gk);
      float4 av1 = *(const float4*)(ain + gk + 4);
      float4 cv0 = *(const float4*)(cin + gk);
      float4 cv1 = *(const float4*)(cin + gk + 4);
      float f0 = fmaxf(fmaf(av0.x, bf2f(val.x & 0xffffu), cv0.x), 0.0f);
      float f1 = fmaxf(fmaf(av0.y, bf2f(val.x >> 16),     cv0.y), 0.0f);
      float f2 = fmaxf(fmaf(av0.z, bf2f(val.y & 0xffffu), cv0.z), 0.0f);
      float f3 = fmaxf(fmaf(av0.w, bf2f(val.y >> 16),     cv0.w), 0.0f);
      float f4 = fmaxf(fmaf(av1.x, bf2f(val.z & 0xffffu), cv1.x), 0.0f);
      float f5 = fmaxf(fmaf(av1.y, bf2f(val.z >> 16),     cv1.y), 0.0f);
      float f6 = fmaxf(fmaf(av1.z, bf2f(val.w & 0xffffu), cv1.z), 0.0f);
      float f7 = fmaxf(fmaf(av1.w, bf2f(val.w >> 16),     cv1.w), 0.0f);
      val = make_uint4(pack2(f0, f1), pack2(f2, f3), pack2(f4, f5), pack2(f6, f7));
    }
    ((uint4*)lA)[c] = val;
  }
  // stage B (W rows, [c][k]) in fragment order
  #pragma unroll
  for (int cc = 0; cc < 8; cc++) {
    int c = tid + cc * 256;
    int lane = c & 63, ct = (c >> 6) & 7, kt = c >> 9;
    int n = lane & 15, quad = lane >> 4;
    ((uint4*)lB)[c] = *(const uint4*)(W + (ct * 16 + n) * DF + kt * 32 + quad * 8);
  }
  __syncthreads();

  int lane = tid & 63, w = tid >> 6;
  int rq = w >> 1, cq = w & 1;  // wave -> 64x64 quadrant
  f32x4 acc[4][4];
  #pragma unroll
  for (int i = 0; i < 4; i++)
    #pragma unroll
    for (int j = 0; j < 4; j++) acc[i][j] = (f32x4){0.f, 0.f, 0.f, 0.f};

  const bf16x8* pA = (const bf16x8*)lA;
  const bf16x8* pB = (const bf16x8*)lB;
  #pragma unroll
  for (int kt = 0; kt < 4; kt++) {
    bf16x8 af[4], bfr[4];
    #pragma unroll
    for (int i = 0; i < 4; i++) af[i] = pA[(kt * 8 + rq * 4 + i) * 64 + lane];
    #pragma unroll
    for (int j = 0; j < 4; j++) bfr[j] = pB[(kt * 8 + cq * 4 + j) * 64 + lane];
    #pragma unroll
    for (int i = 0; i < 4; i++)
      #pragma unroll
      for (int j = 0; j < 4; j++)
        acc[i][j] = __builtin_amdgcn_mfma_f32_16x16x32_bf16(af[i], bfr[j], acc[i][j], 0, 0, 0);
  }

  // epilogue: bias, store bf16, per-column stats
  int mcol = lane & 15, quad = lane >> 4;
  float colS[4] = {0, 0, 0, 0}, colQ[4] = {0, 0, 0, 0};
  #pragma unroll
  for (int j = 0; j < 4; j++) {
    int col = (cq * 4 + j) * 16 + mcol;
    float bv = bias[col];
    #pragma unroll
    for (int i = 0; i < 4; i++) {
      int row0 = rowBase + (rq * 4 + i) * 16 + quad * 4;
      #pragma unroll
      for (int r = 0; r < 4; r++) {
        int row = row0 + r;
        if (row < Nrows) {
          float v = acc[i][j][r] + bv;
          out[(size_t)row * DF + col] = f2bf(v);
          colS[j] += v;
          colQ[j] += v * v;
        }
      }
    }
  }
  int copyOff = (blockIdx.x & (NCOPY - 1)) * DF;
  #pragma unroll
  for (int j = 0; j < 4; j++) {
    float s = colS[j], q = colQ[j];
    s += __shfl_xor(s, 16); q += __shfl_xor(q, 16);
    s += __shfl_xor(s, 32); q += __shfl_xor(q, 32);
    if (quad == 0) {
      int col = (cq * 4 + j) * 16 + mcol;
      atomicAdd(&statS[copyOff + col], s);
      atomicAdd(&statQ[copyOff + col], q);
    }
  }
}

// ---------- finalize BN stats (sum NCOPY copies) into affine a,c ----------
__global__ void k_finalize(const float* __restrict__ s, const float* __restrict__ q,
                           const float* __restrict__ gamma, const float* __restrict__ beta,
                           float* __restrict__ a, float* __restrict__ c, int Nrows) {
  int t = threadIdx.x;
  if (t < DF) {
    float S = 0.f, Q = 0.f;
    #pragma unroll
    for (int i = 0; i < NCOPY; i++) { S += s[i * DF + t]; Q += q[i * DF + t]; }
    float inv_n = 1.0f / (float)Nrows;
    float mean = S * inv_n;
    float var = fmaxf(Q * inv_n - mean * mean, 0.0f);
    float iv = rsqrtf(var + 1e-5f);
    float av = gamma[t] * iv;
    a[t] = av;
    c[t] = beta[t] - mean * av;
  }
}

// ---------- BN apply (bf16 out, optional relu) ----------
__global__ void k_bnapply_bf16(const u16* __restrict__ u, const float* __restrict__ a,
                               const float* __restrict__ c, u16* __restrict__ h, int n8, int relu) {
  int i = blockIdx.x * blockDim.x + threadIdx.x;
  if (i >= n8) return;
  int col = (i * 8) & 127;
  float4 a0 = *(const float4*)(a + col), a1v = *(const float4*)(a + col + 4);
  float4 c0 = *(const float4*)(c + col), c1v = *(const float4*)(c + col + 4);
  uint4 v = ((const uint4*)u)[i];
  float f0 = fmaf(a0.x, bf2f(v.x & 0xffffu), c0.x);
  float f1 = fmaf(a0.y, bf2f(v.x >> 16),     c0.y);
  float f2 = fmaf(a0.z, bf2f(v.y & 0xffffu), c0.z);
  float f3 = fmaf(a0.w, bf2f(v.y >> 16),     c0.w);
  float f4 = fmaf(a1v.x, bf2f(v.z & 0xffffu), c1v.x);
  float f5 = fmaf(a1v.y, bf2f(v.z >> 16),     c1v.y);
  float f6 = fmaf(a1v.z, bf2f(v.w & 0xffffu), c1v.z);
  float f7 = fmaf(a1v.w, bf2f(v.w >> 16),     c1v.w);
  if (relu) {
    f0 = fmaxf(f0, 0.f); f1 = fmaxf(f1, 0.f); f2 = fmaxf(f2, 0.f); f3 = fmaxf(f3, 0.f);
    f4 = fmaxf(f4, 0.f); f5 = fmaxf(f5, 0.f); f6 = fmaxf(f6, 0.f); f7 = fmaxf(f7, 0.f);
  }
  ((uint4*)h)[i] = make_uint4(pack2(f0, f1), pack2(f2, f3), pack2(f4, f5), pack2(f6, f7));
}

// ---------- BN apply, f32 out (final layer, no relu) ----------
__global__ void k_bnapply_f32(const u16* __restrict__ u, const float* __restrict__ a,
                              const float* __restrict__ c, float* __restrict__ out, int n8) {
  int i = blockIdx.x * blockDim.x + threadIdx.x;
  if (i >= n8) return;
  int col = (i * 8) & 127;
  float4 a0 = *(const float4*)(a + col), a1v = *(const float4*)(a + col + 4);
  float4 c0 = *(const float4*)(c + col), c1v = *(const float4*)(c + col + 4);
  uint4 v = ((const uint4*)u)[i];
  float4 o0, o1;
  o0.x = fmaf(a0.x, bf2f(v.x & 0xffffu), c0.x);
  o0.y = fmaf(a0.y, bf2f(v.x >> 16),     c0.y);
  o0.z = fmaf(a0.z, bf2f(v.y & 0xffffu), c0.z);
  o0.w = fmaf(a0.w, bf2f(v.y >> 16),     c0.w);
  o1.x = fmaf(a1v.x, bf2f(v.z & 0xffffu), c1v.x);
  o1.y = fmaf(a1v.y, bf2f(v.z >> 16),     c1v.y);
  o1.z = fmaf(a1v.z, bf2f(v.w & 0xffffu), c1v.z);
  o1.w = fmaf(a1v.w, bf2f(v.w >> 16),     c1v.w);
  ((float4*)out)[i * 2] = o0;
  ((float4*)out)[i * 2 + 1] = o1;
}

extern "C" void kernel_launch(void* const* d_in, const int* in_sizes, int n_in,
                              void* d_out, int out_size, void* d_ws, size_t ws_size,
                              hipStream_t stream) {
  const float* x    = (const float*)d_in[0];
  const int*   ei   = (const int*)d_in[1];
  const float* W1   = (const float*)d_in[2];
  const float* b1   = (const float*)d_in[3];
  const float* g1   = (const float*)d_in[4];
  const float* bt1  = (const float*)d_in[5];
  const float* W2   = (const float*)d_in[6];
  const float* b2   = (const float*)d_in[7];
  const float* eps  = (const float*)d_in[8];
  const float* gout = (const float*)d_in[9];
  const float* btout= (const float*)d_in[10];

  int N = in_sizes[0] / DF;
  int E = in_sizes[1] / 2;
  int L = in_sizes[8];

  char* ws = (char*)d_ws;
  size_t off = 0;
  auto alloc = [&](size_t bytes) -> void* {
    void* p = ws + off;
    off += (bytes + 255) & ~(size_t)255;
    return p;
  };
  u16* Xb     = (u16*)alloc((size_t)N * DF * 2);
  u16* bufA   = (u16*)alloc((size_t)N * DF * 2);
  u16* bufB   = (u16*)alloc((size_t)N * DF * 2);
  int* rowptr = (int*)alloc((size_t)(N + 1) * 4);
  int* adj    = (int*)alloc((size_t)E * 4);
  uint2* part = (uint2*)alloc((size_t)E * 8);
  int* bCount = (int*)alloc(NBUCK * 4);
  int* bStart = (int*)alloc((NBUCK + 1) * 4);
  int* bCur   = (int*)alloc(NBUCK * 4);
  u16* W1b    = (u16*)alloc((size_t)L * DF * DF * 2);
  u16* W2b    = (u16*)alloc((size_t)L * DF * DF * 2);
  float* stats= (float*)alloc((size_t)L * 4 * STATW * 4);
  float* coefs= (float*)alloc((size_t)L * 4 * DF * 4);

  hipMemsetAsync(bCount, 0, NBUCK * 4, stream);
  hipMemsetAsync(stats, 0, (size_t)L * 4 * STATW * 4, stream);

  int n4x = N * DF / 4;
  k_cvt_f32_bf16<<<(n4x + 255) / 256, 256, 0, stream>>>(x, Xb, n4x);
  int n4w = L * DF * DF / 4;
  k_cvt_f32_bf16<<<(n4w + 255) / 256, 256, 0, stream>>>(W1, W1b, n4w);
  k_cvt_f32_bf16<<<(n4w + 255) / 256, 256, 0, stream>>>(W2, W2b, n4w);

  const int* srcI = ei;
  const int* dstI = ei + E;
  int nbuckets = (N + BUCK_SIZE - 1) >> BUCK_SHIFT;
  k_p1<<<512, 256, 0, stream>>>(dstI, bCount, E);
  k_pscan<<<1, 256, 0, stream>>>(bCount, bStart, bCur, rowptr, N, E);
  k_p2<<<(E + P2_CHUNK - 1) / P2_CHUNK, 256, 0, stream>>>(srcI, dstI, bCur, part, E);
  k_p3<<<nbuckets, 256, 0, stream>>>(part, bStart, rowptr, adj, N);

  // H (post BN+ReLU inter-layer activations) lives in bufB after each layer's
  // bnapply; bufA/bufB also serve as z/t ping-pong inside the layer:
  //   aggr:  H(or Xb) -> bufA ; gemm1: bufA -> bufB ; gemm2: bufB -> bufA ;
  //   bnapply: bufA -> bufB (=H)   [final layer: bufA -> d_out f32]
  int gblocks = (N + 127) / 128;
  int n8 = N * DF / 8;
  for (int l = 0; l < L; l++) {
    float* S1 = stats + (size_t)(l * 4 + 0) * STATW;
    float* Q1 = stats + (size_t)(l * 4 + 1) * STATW;
    float* S2 = stats + (size_t)(l * 4 + 2) * STATW;
    float* Q2 = stats + (size_t)(l * 4 + 3) * STATW;
    float* a1 = coefs + (size_t)(l * 4 + 0) * DF;
    float* c1 = coefs + (size_t)(l * 4 + 1) * DF;
    float* a2 = coefs + (size_t)(l * 4 + 2) * DF;
    float* c2 = coefs + (size_t)(l * 4 + 3) * DF;
    const u16* H = (l == 0) ? Xb : bufB;
    // z = (1+eps)H + sum msg(H[src]); msg has relu only at l=0 (H>=0 for l>0)
    k_aggr<<<(N + 3) / 4, 256, 0, stream>>>(H, H, rowptr, adj, eps, l,
                                            (l == 0) ? 1 : 0, bufA, N);
    // t = z @ W1^T + b1, stats
    k_gemm<<<gblocks, 256, 0, stream>>>(bufA, W1b + l * DF * DF, b1 + l * DF,
                                        nullptr, nullptr, 0, S1, Q1, bufB, N);
    k_finalize<<<1, 128, 0, stream>>>(S1, Q1, g1 + l * DF, bt1 + l * DF, a1, c1, N);
    // u = relu(BN1(t)) @ W2^T + b2, stats
    k_gemm<<<gblocks, 256, 0, stream>>>(bufB, W2b + l * DF * DF, b2 + l * DF,
                                        a1, c1, 1, S2, Q2, bufA, N);
    k_finalize<<<1, 128, 0, stream>>>(S2, Q2, gout + l * DF, btout + l * DF, a2, c2, N);
    if (l < L - 1) {
      k_bnapply_bf16<<<(n8 + 255) / 256, 256, 0, stream>>>(bufA, a2, c2, bufB, n8, 1);
    } else {
      k_bnapply_f32<<<(n8 + 255) / 256, 256, 0, stream>>>(bufA, a2, c2, (float*)d_out, n8);
    }
  }
}